// Round 24
// baseline (361.797 us; speedup 1.0000x reference)
//
#include <hip/hip_runtime.h>
#include <hip/hip_bf16.h>

#define NL 6
#define DT 6144
#define DM 768
#define TOK 128

// encode: r16 structure -- measured ~27-33 us warm
#define EF 32
#define EK 256
#define ENST (DM / EK)
#define NVE (2 * ENST)

// decode partials: FULL-ROW contiguous streaming (this round's change)
#define NFCD 12
#define FCD (DT / NFCD)       // 512 features per block
#define NSTEPD (FCD / 16)     // 32 16-row steps
#define PT (TOK * DM)         // 98304 elems per partial tile

// fallback (atomic) decode config = r16 chassis
#define TDA 256
#define NTDA 3
#define FCA 768
#define NFCA 8
#define NSTEPA (FCA / 32)

using bf16x8 = __attribute__((ext_vector_type(8))) short;
using f32x4  = __attribute__((ext_vector_type(4))) float;

typedef unsigned int u32;
typedef __attribute__((address_space(1))) const u32 gu32;
typedef __attribute__((address_space(3))) u32 lu32;

// async global->LDS, 16B/lane; one contiguous aligned 1KB block per instr.
__device__ __forceinline__ void stage16(const float* g, float* l) {
  __builtin_amdgcn_global_load_lds((gu32*)g, (lu32*)l, 16, 0, 0);
}

__device__ __forceinline__ short f2bf(float f) {
  union { float f; unsigned u; } c; c.f = f;
  unsigned u = c.u;
  u += 0x7fffu + ((u >> 16) & 1u);
  return (short)(u >> 16);
}

__device__ __forceinline__ float bf2f(ushort u) {
  union { unsigned u; float f; } c; c.u = ((unsigned)u) << 16;
  return c.f;
}

// out = b_dec broadcast (fallback init; partials path overwrites), xb = bf16(x)
__global__ void initcvt_k(const float* __restrict__ b_dec,
                          const float* __restrict__ x,
                          float* __restrict__ out, ushort* __restrict__ xb) {
  int idx = blockIdx.x * 256 + threadIdx.x;
  if (idx < NL * TOK * DM) {
    out[idx] = b_dec[(idx / (TOK * DM)) * DM + (idx % DM)];
    xb[idx] = (ushort)f2bf(x[idx]);
  }
}

// acts[l][n][f] = relu(x[l] @ W_enc[l]^T + b_enc[l]). r16 chassis, untouched.
__global__ __launch_bounds__(256, 2) void encode_k(
    const ushort* __restrict__ xb, const float* __restrict__ W_enc,
    const float* __restrict__ b_enc, ushort* __restrict__ acts)
{
  __shared__ float lw[2][EF][EK];

  const int l  = blockIdx.x / 96;
  const int fp = (blockIdx.x % 96) * 64;
  const int w    = threadIdx.x >> 6;
  const int lane = threadIdx.x & 63;
  const int lo = lane & 15, hi = lane >> 4;

  const float*  We = W_enc + ((size_t)l * DT + fp) * DM;
  const ushort* Xb = xb + (size_t)l * TOK * DM;

  f32x4 acc[2][2];
  #pragma unroll
  for (int mi = 0; mi < 2; ++mi)
    #pragma unroll
    for (int ni = 0; ni < 2; ++ni)
      acc[mi][ni] = f32x4{0.f, 0.f, 0.f, 0.f};

  #pragma unroll
  for (int q = 0; q < 8; ++q) {
    const int row = w * 8 + q;
    stage16(We + (size_t)row * DM + (lane ^ (row & 7)) * 4, &lw[0][row][0]);
  }
  __syncthreads();

  int cur = 0;
  #pragma unroll 1
  for (int v = 0; v < NVE; ++v) {
    const int tt = v / ENST;
    const int st = v % ENST;

    if (v + 1 < NVE) {
      const int tt2 = (v + 1) / ENST;
      const int st2 = (v + 1) % ENST;
      #pragma unroll
      for (int q = 0; q < 8; ++q) {
        const int row = w * 8 + q;
        stage16(We + (size_t)(tt2 * EF + row) * DM + st2 * EK + (lane ^ (row & 7)) * 4,
                &lw[cur ^ 1][row][0]);
      }
    }

    const int sw = lo & 7;
    #pragma unroll
    for (int ks = 0; ks < EK / 32; ++ks) {
      bf16x8 a[2], b[2];
      #pragma unroll
      for (int mi = 0; mi < 2; ++mi)
        a[mi] = *(const bf16x8*)(Xb + (size_t)(w * 32 + mi * 16 + lo) * DM
                                 + st * EK + ks * 32 + hi * 8);
      #pragma unroll
      for (int ni = 0; ni < 2; ++ni) {
        const int c0 = (ks * 8 + hi * 2) ^ sw;
        const int c1 = (ks * 8 + hi * 2 + 1) ^ sw;
        const float4 b0 = *(const float4*)&lw[cur][ni * 16 + lo][c0 * 4];
        const float4 b1 = *(const float4*)&lw[cur][ni * 16 + lo][c1 * 4];
        b[ni][0] = f2bf(b0.x); b[ni][1] = f2bf(b0.y);
        b[ni][2] = f2bf(b0.z); b[ni][3] = f2bf(b0.w);
        b[ni][4] = f2bf(b1.x); b[ni][5] = f2bf(b1.y);
        b[ni][6] = f2bf(b1.z); b[ni][7] = f2bf(b1.w);
      }

      #pragma unroll
      for (int mi = 0; mi < 2; ++mi)
        #pragma unroll
        for (int ni = 0; ni < 2; ++ni)
          acc[mi][ni] = __builtin_amdgcn_mfma_f32_16x16x32_bf16(a[mi], b[ni], acc[mi][ni], 0, 0, 0);
    }

    if (st == ENST - 1) {
      #pragma unroll
      for (int ni = 0; ni < 2; ++ni) {
        const int f = fp + tt * EF + ni * 16 + lo;
        const float bias = b_enc[l * DT + f];
        #pragma unroll
        for (int mi = 0; mi < 2; ++mi) {
          #pragma unroll
          for (int rr = 0; rr < 4; ++rr) {
            const int n = w * 32 + mi * 16 + hi * 4 + rr;
            float vv = acc[mi][ni][rr] + bias;
            vv = vv > 0.f ? vv : 0.f;
            acts[((size_t)l * TOK + n) * DT + f] = (ushort)f2bf(vv);
            acc[mi][ni][rr] = 0.f;
          }
        }
      }
    }

    __syncthreads();
    cur ^= 1;
  }
}

__device__ const int PI_[21]  = {0,0,0,0,0,0, 1,1,1,1,1, 2,2,2,2, 3,3,3, 4,4, 5};
__device__ const int PJ_[21]  = {0,1,2,3,4,5, 1,2,3,4,5, 2,3,4,5, 3,4,5, 4,5, 5};
__device__ const int OFFI_[6] = {0, 6, 11, 15, 18, 20};

// FULL-ROW decode: block (pair p, f-chunk c) covers ALL 768 d-cols; its W
// reads tile one CONTIGUOUS 1.5 MB region (512 rows x 3 KB). 16-row k-steps
// via 16x16x32 MFMA with upper K-half zeroed (exact). 1024 thr = 16 waves
// (2 m x 8 d); 96 KB LDS dbuf; 252 blocks = 1/CU, one full round.
__global__ __launch_bounds__(1024, 4) void decode_part_k(
    const ushort* __restrict__ acts, const float* __restrict__ W_dec,
    ushort* __restrict__ part)
{
  __shared__ float lw[2][16][DM];   // 96 KB

  const int bid = blockIdx.x;
  const int p = bid / NFCD, c = bid % NFCD;
  const int i = PI_[p], j = PJ_[p];
  const int w    = threadIdx.x >> 6;      // 0..15
  const int mw   = w >> 3;                // 0..1 (token half)
  const int dw   = w & 7;                 // 0..7 (d-slice of 96)
  const int lane = threadIdx.x & 63;
  const int lo = lane & 15, hi = lane >> 4;
  const int fb = c * FCD;
  const int m0 = mw * 64;
  const int n0 = dw * 96;
  const int khalf = (hi < 2) ? 1 : 0;     // lanes with k<16 carry real data

  const float*  Wb = W_dec + ((size_t)(i * NL + j) * DT + fb) * DM;
  const ushort* Ab = acts + (size_t)i * TOK * DT + fb;

  f32x4 acc[4][6];
  #pragma unroll
  for (int mi = 0; mi < 4; ++mi)
    #pragma unroll
    for (int ni = 0; ni < 6; ++ni)
      acc[mi][ni] = f32x4{0.f, 0.f, 0.f, 0.f};

  // stage step 0: wave w stages row w -- 3 contiguous 1KB chunks = full 3KB row
  #pragma unroll
  for (int q = 0; q < 3; ++q)
    stage16(Wb + (size_t)w * DM + q * 256 + lane * 4, &lw[0][w][q * 256]);
  __syncthreads();

  int cur = 0;
  #pragma unroll 1
  for (int s = 0; s < NSTEPD; ++s) {
    if (s + 1 < NSTEPD) {
      const float* Ws = Wb + (size_t)((s + 1) * 16 + w) * DM;
      #pragma unroll
      for (int q = 0; q < 3; ++q)
        stage16(Ws + q * 256 + lane * 4, &lw[cur ^ 1][w][q * 256]);
    }

    const int ka = khalf ? (s * 16 + hi * 8) : 0;   // in-bounds addr for all lanes
    #pragma unroll
    for (int mh = 0; mh < 2; ++mh) {
      bf16x8 a[2];
      #pragma unroll
      for (int u = 0; u < 2; ++u) {
        const int tok = m0 + (mh * 2 + u) * 16 + lo;
        bf16x8 av = *(const bf16x8*)(Ab + (size_t)tok * DT + ka);
        #pragma unroll
        for (int e = 0; e < 8; ++e) a[u][e] = khalf ? av[e] : (short)0;
      }
      #pragma unroll
      for (int ni = 0; ni < 6; ++ni) {
        const int col = n0 + ni * 16 + lo;
        bf16x8 b;
        #pragma unroll
        for (int e = 0; e < 8; ++e) {
          const int row = khalf ? (hi * 8 + e) : 0;
          const float v = lw[cur][row][col];
          b[e] = khalf ? f2bf(v) : (short)0;
        }
        #pragma unroll
        for (int u = 0; u < 2; ++u)
          acc[mh * 2 + u][ni] = __builtin_amdgcn_mfma_f32_16x16x32_bf16(
              a[u], b, acc[mh * 2 + u][ni], 0, 0, 0);
      }
    }

    __syncthreads();
    cur ^= 1;
  }

  ushort* pp = part + (size_t)bid * PT;
  #pragma unroll
  for (int ni = 0; ni < 6; ++ni) {
    const int d = n0 + ni * 16 + lo;
    #pragma unroll
    for (int mi = 0; mi < 4; ++mi)
      #pragma unroll
      for (int rr = 0; rr < 4; ++rr)
        pp[(size_t)(m0 + mi * 16 + hi * 4 + rr) * DM + d] = (ushort)f2bf(acc[mi][ni][rr]);
  }
}

// out[j][n][d] = b_dec[j][d] + sum_{i<=j} sum_c bf2f(part[(p*NFCD+c)][n][d])
__global__ void reduce_k(const ushort* __restrict__ part,
                         const float* __restrict__ b_dec,
                         float* __restrict__ out)
{
  const int t8 = blockIdx.x * 256 + threadIdx.x;
  if (t8 >= NL * TOK * DM / 8) return;
  const int idx = t8 * 8;
  const int j   = idx / (TOK * DM);
  const int rem = idx % (TOK * DM);        // n*DM + d (d multiple of 8)
  const int dd  = rem % DM;

  float s[8];
  #pragma unroll
  for (int e = 0; e < 8; ++e) s[e] = b_dec[j * DM + dd + e];

  for (int i = 0; i <= j; ++i) {
    const int p = OFFI_[i] + (j - i);
    const ushort* pb = part + (size_t)p * NFCD * PT + rem;
    #pragma unroll
    for (int c = 0; c < NFCD; ++c) {
      bf16x8 v = *(const bf16x8*)(pb + (size_t)c * PT);
      #pragma unroll
      for (int e = 0; e < 8; ++e) s[e] += bf2f((ushort)v[e]);
    }
  }
  #pragma unroll
  for (int e = 0; e < 8; ++e) out[idx + e] = s[e];
}

// fallback (ws too small): r16-style 4-wave LDS decode with atomics
__global__ __launch_bounds__(256, 2) void decode_atomic_k(
    const ushort* __restrict__ acts, const float* __restrict__ W_dec,
    float* __restrict__ out)
{
  __shared__ float lw[2][32][TDA];

  const int bid = blockIdx.x;
  const int p  = bid / (NTDA * NFCA);
  const int rm = bid % (NTDA * NFCA);
  const int c  = rm / NTDA;
  const int t  = rm % NTDA;
  const int i = PI_[p], j = PJ_[p];
  const int w = threadIdx.x >> 6;
  const int lane = threadIdx.x & 63;
  const int lo = lane & 15, hi = lane >> 4;
  const int fb = c * FCA;

  const float*  Wb = W_dec + ((size_t)(i * NL + j) * DT + fb) * DM + t * TDA;
  const ushort* Ab = acts + (size_t)i * TOK * DT + fb;

  f32x4 acc[8][4];
  #pragma unroll
  for (int mi = 0; mi < 8; ++mi)
    #pragma unroll
    for (int ni = 0; ni < 4; ++ni)
      acc[mi][ni] = f32x4{0.f, 0.f, 0.f, 0.f};

  #pragma unroll
  for (int q = 0; q < 8; ++q) {
    const int row = w * 8 + q;
    stage16(Wb + (size_t)row * DM + lane * 4, &lw[0][row][0]);
  }
  __syncthreads();

  int cur = 0;
  #pragma unroll 1
  for (int s = 0; s < NSTEPA; ++s) {
    if (s + 1 < NSTEPA) {
      const float* Ws = Wb + (size_t)(s + 1) * 32 * DM;
      #pragma unroll
      for (int q = 0; q < 8; ++q) {
        const int row = w * 8 + q;
        stage16(Ws + (size_t)row * DM + lane * 4, &lw[cur ^ 1][row][0]);
      }
    }

    bf16x8 a[8];
    #pragma unroll
    for (int mi = 0; mi < 8; ++mi)
      a[mi] = *(const bf16x8*)(Ab + (size_t)(mi * 16 + lo) * DT + s * 32 + hi * 8);

    bf16x8 bb[4];
    #pragma unroll
    for (int ni = 0; ni < 4; ++ni) {
      const int col = w * 64 + ni * 16 + lo;
      #pragma unroll
      for (int e = 0; e < 8; ++e)
        bb[ni][e] = f2bf(lw[cur][hi * 8 + e][col]);
    }

    #pragma unroll
    for (int mi = 0; mi < 8; ++mi)
      #pragma unroll
      for (int ni = 0; ni < 4; ++ni)
        acc[mi][ni] = __builtin_amdgcn_mfma_f32_16x16x32_bf16(a[mi], bb[ni], acc[mi][ni], 0, 0, 0);

    __syncthreads();
    cur ^= 1;
  }

  float* oj = out + (size_t)j * TOK * DM;
  #pragma unroll
  for (int ni = 0; ni < 4; ++ni) {
    const int d = t * TDA + w * 64 + ni * 16 + lo;
    #pragma unroll
    for (int mi = 0; mi < 8; ++mi)
      #pragma unroll
      for (int rr = 0; rr < 4; ++rr)
        atomicAdd(oj + (size_t)(mi * 16 + hi * 4 + rr) * DM + d, acc[mi][ni][rr]);
  }
}

extern "C" void kernel_launch(void* const* d_in, const int* in_sizes, int n_in,
                              void* d_out, int out_size, void* d_ws, size_t ws_size,
                              hipStream_t stream) {
  const float* x     = (const float*)d_in[0];
  const float* W_enc = (const float*)d_in[1];
  const float* b_enc = (const float*)d_in[2];
  const float* b_dec = (const float*)d_in[3];
  const float* W_dec = (const float*)d_in[4];
  float* out = (float*)d_out;

  const size_t actsB = (size_t)NL * TOK * DT * 2;     // 9.44 MB
  const size_t xbB   = (size_t)NL * TOK * DM * 2;     // 1.18 MB
  const size_t partB = (size_t)21 * NFCD * PT * 2;    // 49.5 MB bf16

  ushort* acts = (ushort*)d_ws;
  ushort* xb   = (ushort*)((char*)d_ws + actsB);
  ushort* part = (ushort*)((char*)d_ws + actsB + xbB);

  initcvt_k<<<dim3((NL * TOK * DM + 255) / 256), dim3(256), 0, stream>>>(b_dec, x, out, xb);
  encode_k<<<dim3(NL * 96), dim3(256), 0, stream>>>(xb, W_enc, b_enc, acts);

  if (ws_size >= actsB + xbB + partB) {
    decode_part_k<<<dim3(21 * NFCD), dim3(1024), 0, stream>>>(acts, W_dec, part);
    reduce_k<<<dim3((NL * TOK * DM / 8 + 255) / 256), dim3(256), 0, stream>>>(part, b_dec, out);
  } else {
    decode_atomic_k<<<dim3(21 * NFCA * NTDA), dim3(256), 0, stream>>>(acts, W_dec, out);
  }
}

// Round 25
// 181.426 us; speedup vs baseline: 1.9942x; 1.9942x over previous
//
#include <hip/hip_runtime.h>
#include <hip/hip_bf16.h>

#define NL 6
#define DT 6144
#define DM 768
#define TOK 128

// encode: r16 structure -- measured ~27-33 us warm
#define EF 32
#define EK 256
#define ENST (DM / EK)
#define NVE (2 * ENST)

// decode partials: r23 best config -- 8 waves/block, NFC=8, 504 blocks
#define TD 256
#define NTD 3
#define FC 768
#define NFC 8
#define NSTEP (FC / 32)   // 24 k-steps
#define TILE_ELEMS (TOK * TD)

using bf16x8 = __attribute__((ext_vector_type(8))) short;
using f32x4  = __attribute__((ext_vector_type(4))) float;

typedef unsigned int u32;
typedef __attribute__((address_space(1))) const u32 gu32;
typedef __attribute__((address_space(3))) u32 lu32;

// async global->LDS, 16B/lane; RULE (r10/r13): one contiguous aligned 1KB
// block per instruction.
__device__ __forceinline__ void stage16(const float* g, float* l) {
  __builtin_amdgcn_global_load_lds((gu32*)g, (lu32*)l, 16, 0, 0);
}

__device__ __forceinline__ short f2bf(float f) {
  union { float f; unsigned u; } c; c.f = f;
  unsigned u = c.u;
  u += 0x7fffu + ((u >> 16) & 1u);
  return (short)(u >> 16);
}

__device__ __forceinline__ float bf2f(ushort u) {
  union { unsigned u; float f; } c; c.u = ((unsigned)u) << 16;
  return c.f;
}

// out = b_dec broadcast (fallback init; partials path overwrites), xb = bf16(x)
__global__ void initcvt_k(const float* __restrict__ b_dec,
                          const float* __restrict__ x,
                          float* __restrict__ out, ushort* __restrict__ xb) {
  int idx = blockIdx.x * 256 + threadIdx.x;
  if (idx < NL * TOK * DM) {
    out[idx] = b_dec[(idx / (TOK * DM)) * DM + (idx % DM)];
    xb[idx] = (ushort)f2bf(x[idx]);
  }
}

// acts[l][n][f] = relu(x[l] @ W_enc[l]^T + b_enc[l]). r16 chassis, untouched.
__global__ __launch_bounds__(256, 2) void encode_k(
    const ushort* __restrict__ xb, const float* __restrict__ W_enc,
    const float* __restrict__ b_enc, ushort* __restrict__ acts)
{
  __shared__ float lw[2][EF][EK];

  const int l  = blockIdx.x / 96;
  const int fp = (blockIdx.x % 96) * 64;
  const int w    = threadIdx.x >> 6;
  const int lane = threadIdx.x & 63;
  const int lo = lane & 15, hi = lane >> 4;

  const float*  We = W_enc + ((size_t)l * DT + fp) * DM;
  const ushort* Xb = xb + (size_t)l * TOK * DM;

  f32x4 acc[2][2];
  #pragma unroll
  for (int mi = 0; mi < 2; ++mi)
    #pragma unroll
    for (int ni = 0; ni < 2; ++ni)
      acc[mi][ni] = f32x4{0.f, 0.f, 0.f, 0.f};

  #pragma unroll
  for (int q = 0; q < 8; ++q) {
    const int row = w * 8 + q;
    stage16(We + (size_t)row * DM + (lane ^ (row & 7)) * 4, &lw[0][row][0]);
  }
  __syncthreads();

  int cur = 0;
  #pragma unroll 1
  for (int v = 0; v < NVE; ++v) {
    const int tt = v / ENST;
    const int st = v % ENST;

    if (v + 1 < NVE) {
      const int tt2 = (v + 1) / ENST;
      const int st2 = (v + 1) % ENST;
      #pragma unroll
      for (int q = 0; q < 8; ++q) {
        const int row = w * 8 + q;
        stage16(We + (size_t)(tt2 * EF + row) * DM + st2 * EK + (lane ^ (row & 7)) * 4,
                &lw[cur ^ 1][row][0]);
      }
    }

    const int sw = lo & 7;
    #pragma unroll
    for (int ks = 0; ks < EK / 32; ++ks) {
      bf16x8 a[2], b[2];
      #pragma unroll
      for (int mi = 0; mi < 2; ++mi)
        a[mi] = *(const bf16x8*)(Xb + (size_t)(w * 32 + mi * 16 + lo) * DM
                                 + st * EK + ks * 32 + hi * 8);
      #pragma unroll
      for (int ni = 0; ni < 2; ++ni) {
        const int c0 = (ks * 8 + hi * 2) ^ sw;
        const int c1 = (ks * 8 + hi * 2 + 1) ^ sw;
        const float4 b0 = *(const float4*)&lw[cur][ni * 16 + lo][c0 * 4];
        const float4 b1 = *(const float4*)&lw[cur][ni * 16 + lo][c1 * 4];
        b[ni][0] = f2bf(b0.x); b[ni][1] = f2bf(b0.y);
        b[ni][2] = f2bf(b0.z); b[ni][3] = f2bf(b0.w);
        b[ni][4] = f2bf(b1.x); b[ni][5] = f2bf(b1.y);
        b[ni][6] = f2bf(b1.z); b[ni][7] = f2bf(b1.w);
      }

      #pragma unroll
      for (int mi = 0; mi < 2; ++mi)
        #pragma unroll
        for (int ni = 0; ni < 2; ++ni)
          acc[mi][ni] = __builtin_amdgcn_mfma_f32_16x16x32_bf16(a[mi], b[ni], acc[mi][ni], 0, 0, 0);
    }

    if (st == ENST - 1) {
      #pragma unroll
      for (int ni = 0; ni < 2; ++ni) {
        const int f = fp + tt * EF + ni * 16 + lo;
        const float bias = b_enc[l * DT + f];
        #pragma unroll
        for (int mi = 0; mi < 2; ++mi) {
          #pragma unroll
          for (int rr = 0; rr < 4; ++rr) {
            const int n = w * 32 + mi * 16 + hi * 4 + rr;
            float vv = acc[mi][ni][rr] + bias;
            vv = vv > 0.f ? vv : 0.f;
            acts[((size_t)l * TOK + n) * DT + f] = (ushort)f2bf(vv);
            acc[mi][ni][rr] = 0.f;
          }
        }
      }
    }

    __syncthreads();
    cur ^= 1;
  }
}

__device__ const int PI_[21]  = {0,0,0,0,0,0, 1,1,1,1,1, 2,2,2,2, 3,3,3, 4,4, 5};
__device__ const int PJ_[21]  = {0,1,2,3,4,5, 1,2,3,4,5, 2,3,4,5, 3,4,5, 4,5, 5};
__device__ const int OFFI_[6] = {0, 6, 11, 15, 18, 20};

// 8-WAVE decode (r23, best measured): 512 thr = 2 m-waves x 4 d-waves,
// 16 waves/CU resident; same LDS geometry / staging pattern as the 4-wave
// chassis; plain __syncthreads; bf16 partial stores (zero atomics).
__global__ __launch_bounds__(512, 4) void decode_part_k(
    const ushort* __restrict__ acts, const float* __restrict__ W_dec,
    ushort* __restrict__ part)
{
  __shared__ float lw[2][32][TD];   // 64 KB

  const int bid = blockIdx.x;
  const int p  = bid / (NFC * NTD);
  const int rm = bid % (NFC * NTD);
  const int c  = rm / NTD;
  const int t  = rm % NTD;
  const int i = PI_[p], j = PJ_[p];
  const int w    = threadIdx.x >> 6;   // 0..7
  const int mw   = w >> 2;             // 0..1 (token half)
  const int dwv  = w & 3;              // 0..3 (d-quarter)
  const int lane = threadIdx.x & 63;
  const int lo = lane & 15, hi = lane >> 4;
  const int fb = c * FC;
  const int m0 = mw * 64;
  (void)j;

  const float*  Wb = W_dec + ((size_t)(i * NL + j) * DT + fb) * DM + t * TD;
  const ushort* Ab = acts + (size_t)i * TOK * DT + fb;

  f32x4 acc[4][4];
  #pragma unroll
  for (int mi = 0; mi < 4; ++mi)
    #pragma unroll
    for (int ni = 0; ni < 4; ++ni)
      acc[mi][ni] = f32x4{0.f, 0.f, 0.f, 0.f};

  // stage step 0: 8 waves x 4 rows, one contiguous 1KB per instruction
  #pragma unroll
  for (int q = 0; q < 4; ++q) {
    const int row = w * 4 + q;
    stage16(Wb + (size_t)row * DM + lane * 4, &lw[0][row][0]);
  }
  __syncthreads();

  int cur = 0;
  #pragma unroll 1
  for (int s = 0; s < NSTEP; ++s) {
    if (s + 1 < NSTEP) {
      const float* Ws = Wb + (size_t)(s + 1) * 32 * DM;
      #pragma unroll
      for (int q = 0; q < 4; ++q) {
        const int row = w * 4 + q;
        stage16(Ws + (size_t)row * DM + lane * 4, &lw[cur ^ 1][row][0]);
      }
    }

    bf16x8 a[4];
    #pragma unroll
    for (int mi = 0; mi < 4; ++mi)
      a[mi] = *(const bf16x8*)(Ab + (size_t)(m0 + mi * 16 + lo) * DT + s * 32 + hi * 8);

    bf16x8 bb[4];
    #pragma unroll
    for (int ni = 0; ni < 4; ++ni) {
      const int col = dwv * 64 + ni * 16 + lo;
      #pragma unroll
      for (int e = 0; e < 8; ++e)
        bb[ni][e] = f2bf(lw[cur][hi * 8 + e][col]);
    }

    #pragma unroll
    for (int mi = 0; mi < 4; ++mi)
      #pragma unroll
      for (int ni = 0; ni < 4; ++ni)
        acc[mi][ni] = __builtin_amdgcn_mfma_f32_16x16x32_bf16(a[mi], bb[ni], acc[mi][ni], 0, 0, 0);

    __syncthreads();
    cur ^= 1;
  }

  ushort* pp = part + (size_t)bid * TILE_ELEMS;
  #pragma unroll
  for (int ni = 0; ni < 4; ++ni) {
    const int dl = dwv * 64 + ni * 16 + lo;
    #pragma unroll
    for (int mi = 0; mi < 4; ++mi)
      #pragma unroll
      for (int rr = 0; rr < 4; ++rr)
        pp[(size_t)(m0 + mi * 16 + hi * 4 + rr) * TD + dl] = (ushort)f2bf(acc[mi][ni][rr]);
  }
}

// out[j][n][d] = b_dec[j][d] + sum_{i<=j} sum_c bf2f(part), bf16x8-vectorized.
// 8 consecutive d stay within one t-tile (8 | TD), and tile bases are
// 16B-aligned, so the vector loads are legal. Same per-element sum order.
__global__ void reduce_k(const ushort* __restrict__ part,
                         const float* __restrict__ b_dec,
                         float* __restrict__ out)
{
  const int t8 = blockIdx.x * 256 + threadIdx.x;
  if (t8 >= NL * TOK * DM / 8) return;
  const int idx = t8 * 8;
  const int j   = idx / (TOK * DM);
  const int rem = idx % (TOK * DM);
  const int n   = rem / DM;
  const int d   = rem % DM;          // multiple of 8
  const int t   = d >> 8;
  const int dl  = d & (TD - 1);

  float s[8];
  #pragma unroll
  for (int e = 0; e < 8; ++e) s[e] = b_dec[j * DM + d + e];

  for (int i = 0; i <= j; ++i) {
    const int p = OFFI_[i] + (j - i);
    const ushort* pb = part + ((size_t)(p * NFC) * NTD + t) * TILE_ELEMS
                       + (size_t)n * TD + dl;
    #pragma unroll
    for (int c = 0; c < NFC; ++c) {
      bf16x8 v = *(const bf16x8*)(pb + (size_t)c * NTD * TILE_ELEMS);
      #pragma unroll
      for (int e = 0; e < 8; ++e) s[e] += bf2f((ushort)v[e]);
    }
  }
  #pragma unroll
  for (int e = 0; e < 8; ++e) out[idx + e] = s[e];
}

// fallback (ws too small): r16-style 4-wave LDS decode with atomics
__global__ __launch_bounds__(256, 2) void decode_atomic_k(
    const ushort* __restrict__ acts, const float* __restrict__ W_dec,
    float* __restrict__ out)
{
  __shared__ float lw[2][32][TD];

  const int bid = blockIdx.x;
  const int p  = bid / (NTD * NFC);
  const int rm = bid % (NTD * NFC);
  const int c  = rm / NTD;
  const int t  = rm % NTD;
  const int i = PI_[p], j = PJ_[p];
  const int w = threadIdx.x >> 6;
  const int lane = threadIdx.x & 63;
  const int lo = lane & 15, hi = lane >> 4;
  const int fb = c * FC;

  const float*  Wb = W_dec + ((size_t)(i * NL + j) * DT + fb) * DM + t * TD;
  const ushort* Ab = acts + (size_t)i * TOK * DT + fb;

  f32x4 acc[8][4];
  #pragma unroll
  for (int mi = 0; mi < 8; ++mi)
    #pragma unroll
    for (int ni = 0; ni < 4; ++ni)
      acc[mi][ni] = f32x4{0.f, 0.f, 0.f, 0.f};

  #pragma unroll
  for (int q = 0; q < 8; ++q) {
    const int row = w * 8 + q;
    stage16(Wb + (size_t)row * DM + lane * 4, &lw[0][row][0]);
  }
  __syncthreads();

  int cur = 0;
  #pragma unroll 1
  for (int s = 0; s < NSTEP; ++s) {
    if (s + 1 < NSTEP) {
      const float* Ws = Wb + (size_t)(s + 1) * 32 * DM;
      #pragma unroll
      for (int q = 0; q < 8; ++q) {
        const int row = w * 8 + q;
        stage16(Ws + (size_t)row * DM + lane * 4, &lw[cur ^ 1][row][0]);
      }
    }

    bf16x8 a[8];
    #pragma unroll
    for (int mi = 0; mi < 8; ++mi)
      a[mi] = *(const bf16x8*)(Ab + (size_t)(mi * 16 + lo) * DT + s * 32 + hi * 8);

    bf16x8 bb[4];
    #pragma unroll
    for (int ni = 0; ni < 4; ++ni) {
      const int col = w * 64 + ni * 16 + lo;
      #pragma unroll
      for (int e = 0; e < 8; ++e)
        bb[ni][e] = f2bf(lw[cur][hi * 8 + e][col]);
    }

    #pragma unroll
    for (int mi = 0; mi < 8; ++mi)
      #pragma unroll
      for (int ni = 0; ni < 4; ++ni)
        acc[mi][ni] = __builtin_amdgcn_mfma_f32_16x16x32_bf16(a[mi], bb[ni], acc[mi][ni], 0, 0, 0);

    __syncthreads();
    cur ^= 1;
  }

  float* oj = out + (size_t)j * TOK * DM;
  #pragma unroll
  for (int ni = 0; ni < 4; ++ni) {
    const int d = t * TD + w * 64 + ni * 16 + lo;
    #pragma unroll
    for (int mi = 0; mi < 8; ++mi)
      #pragma unroll
      for (int rr = 0; rr < 4; ++rr)
        atomicAdd(oj + (size_t)(mi * 16 + hi * 4 + rr) * DM + d, acc[mi][ni][rr]);
  }
}

extern "C" void kernel_launch(void* const* d_in, const int* in_sizes, int n_in,
                              void* d_out, int out_size, void* d_ws, size_t ws_size,
                              hipStream_t stream) {
  const float* x     = (const float*)d_in[0];
  const float* W_enc = (const float*)d_in[1];
  const float* b_enc = (const float*)d_in[2];
  const float* b_dec = (const float*)d_in[3];
  const float* W_dec = (const float*)d_in[4];
  float* out = (float*)d_out;

  const size_t actsB = (size_t)NL * TOK * DT * 2;   // 9.44 MB
  const size_t xbB   = (size_t)NL * TOK * DM * 2;   // 1.18 MB
  const size_t partB = (size_t)21 * NFC * NTD * TILE_ELEMS * 2;   // 33 MB bf16

  ushort* acts = (ushort*)d_ws;
  ushort* xb   = (ushort*)((char*)d_ws + actsB);
  ushort* part = (ushort*)((char*)d_ws + actsB + xbB);

  initcvt_k<<<dim3((NL * TOK * DM + 255) / 256), dim3(256), 0, stream>>>(b_dec, x, out, xb);
  encode_k<<<dim3(NL * 96), dim3(256), 0, stream>>>(xb, W_enc, b_enc, acts);

  if (ws_size >= actsB + xbB + partB) {
    decode_part_k<<<dim3(21 * NFC * NTD), dim3(512), 0, stream>>>(acts, W_dec, part);
    reduce_k<<<dim3((NL * TOK * DM / 8 + 255) / 256), dim3(256), 0, stream>>>(part, b_dec, out);
  } else {
    decode_atomic_k<<<dim3(21 * NFC * NTD), dim3(256), 0, stream>>>(acts, W_dec, out);
  }
}